// Round 13
// baseline (2790.689 us; speedup 1.0000x reference)
//
#include <hip/hip_runtime.h>

#define NB 4
#define NH 1024
#define NW 1024
#define NHW (NH * NW)

#define TS 32              // owned tile side; block reads exactly its own 32x32
#define TILE_PX (TS * TS)  // 1024

__device__ __forceinline__ float srgb2lin(float v) {
    return v > 0.04045f ? powf((v + 0.055f) * (1.0f / 1.055f), 2.4f) : v * (1.0f / 12.92f);
}

__device__ __forceinline__ float labf(float t) {
    return t > 0.008856f ? cbrtf(t) : 7.787f * t + 4.0f / 29.0f;
}

// Compute Lab for both images, INTERLEAVED (hw,3) output for gather locality.
__global__ void lab_kernel(const float* __restrict__ I0, const float* __restrict__ I1,
                           float* __restrict__ lab0, float* __restrict__ lab1) {
    int idx = blockIdx.x * blockDim.x + threadIdx.x;
    const int total = 2 * NB * NHW;
    if (idx >= total) return;
    int img = (idx >= NB * NHW) ? 1 : 0;
    int p = idx - img * NB * NHW;
    int b = p / NHW;
    int hw = p - b * NHW;
    const float* src = (img ? I1 : I0) + (size_t)b * 3 * NHW + hw;
    float* dst = (img ? lab1 : lab0) + ((size_t)b * NHW + hw) * 3;

    float r = srgb2lin(src[0]);
    float g = srgb2lin(src[NHW]);
    float bl = srgb2lin(src[2 * NHW]);

    float X = (0.412453f * r + 0.35758f * g + 0.180423f * bl) * (1.0f / 0.95047f);
    float Y = (0.212671f * r + 0.71516f * g + 0.072169f * bl);
    float Z = (0.019334f * r + 0.119193f * g + 0.950227f * bl) * (1.0f / 1.08883f);

    float fx = labf(X);
    float fy = labf(Y);
    float fz = labf(Z);

    dst[0] = 116.0f * fy - 16.0f;
    dst[1] = 500.0f * (fx - fy);
    dst[2] = 200.0f * (fy - fz);
}

// z-metric + exp + premultiply, both directions in one launch (z in [0,2*NB)).
__global__ __launch_bounds__(256) void wmap_kernel(
        const float* __restrict__ lab0, const float* __restrict__ lab1,
        const float* __restrict__ I0, const float* __restrict__ I1,
        const float* __restrict__ f01, const float* __restrict__ f10,
        float4* __restrict__ pm0, float4* __restrict__ pm1) {
    const int z = blockIdx.z;
    const int dir = z >> 2;            // NB == 4
    const int b = z & (NB - 1);
    const int tx = threadIdx.x & 31;
    const int ty = threadIdx.x >> 5;
    const int x = blockIdx.x * 32 + tx;
    const int y = blockIdx.y * 8 + ty;
    const int hw = y * NW + x;

    const float* la  = (dir ? lab1 : lab0) + (size_t)b * NHW * 3;
    const float* lb  = (dir ? lab0 : lab1) + (size_t)b * NHW * 3;
    const float* img = (dir ? I1 : I0) + (size_t)b * 3 * NHW;
    const float* fb  = (dir ? f10 : f01) + (size_t)b * 2 * NHW;
    float4* pm = (dir ? pm1 : pm0) + (size_t)b * NHW;

    const float fy_d = fb[hw];
    const float fx_d = fb[NHW + hw];

    float base_y = -1.0f + 2.0f * (float)y / (float)(NH - 1);
    float base_x = -1.0f + 2.0f * (float)x / (float)(NW - 1);
    float gy = 2.0f * fy_d / (float)NH + base_y;
    float gx = 2.0f * fx_d / (float)NW + base_x;
    float ys = fminf(fmaxf(((gy + 1.0f) * (float)NH - 1.0f) * 0.5f, 0.0f), (float)(NH - 1));
    float xs = fminf(fmaxf(((gx + 1.0f) * (float)NW - 1.0f) * 0.5f, 0.0f), (float)(NW - 1));
    float y0f = floorf(ys), x0f = floorf(xs);
    int y0 = (int)y0f, x0 = (int)x0f;
    int y1 = min(y0 + 1, NH - 1), x1 = min(x0 + 1, NW - 1);
    float wy = ys - y0f, wx = xs - x0f;

    const float* p00 = lb + (size_t)(y0 * NW + x0) * 3;
    const float* p01 = lb + (size_t)(y0 * NW + x1) * 3;
    const float* p10 = lb + (size_t)(y1 * NW + x0) * 3;
    const float* p11 = lb + (size_t)(y1 * NW + x1) * 3;
    const float* pa  = la + (size_t)hw * 3;

    float ss = 0.0f;
#pragma unroll
    for (int c = 0; c < 3; ++c) {
        float top = p00[c] * (1.0f - wx) + p01[c] * wx;
        float bot = p10[c] * (1.0f - wx) + p11[c] * wx;
        float v = top * (1.0f - wy) + bot * wy;
        float d = pa[c] - v;
        ss += d * d;
    }
    float w = expf(-0.1f * sqrtf(ss));

    pm[hw] = make_float4(img[hw] * w, img[NHW + hw] * w, img[2 * NHW + hw] * w, w);
}

// Halo-free ownership splat: 1 px/thread, block = exactly its 32x32 tile
// (1x work -> 8.4M iterations vs 33.5M with the halo-4x scheme). Taps in own
// tile accumulate in LDS; all other taps go straight to the ovf buffer via
// scattered global atomics (proven non-binding in r11/r12). Single code path:
// sources always in-bounds, no halo/covered/interior logic, no kk loop.
__global__ __launch_bounds__(1024, 2) void splat_own_kernel(
        const float4* __restrict__ pm0, const float4* __restrict__ pm1,
        const float* __restrict__ f01, const float* __restrict__ f10,
        float4* __restrict__ acc4,    // [2*NB*NHW) float4, dir-major
        float4* __restrict__ ovf) {   // [2*NB*NHW) float4, dir-major (zeroed)
    __shared__ float acc[4][TILE_PX];   // 16 KB planar

    const int t = threadIdx.x;
    const int z = blockIdx.z;
    const int dir = z >> 2;
    const int b = z & (NB - 1);
    const int tx0 = blockIdx.x * TS;
    const int ty0 = blockIdx.y * TS;

    acc[0][t] = 0.0f; acc[1][t] = 0.0f; acc[2][t] = 0.0f; acc[3][t] = 0.0f;
    __syncthreads();

    const float4* pm = (dir ? pm1 : pm0) + (size_t)b * NHW;
    const float* fb  = (dir ? f10 : f01) + (size_t)b * 2 * NHW;
    float4* a4 = acc4 + ((size_t)dir * NB + b) * NHW;
    float4* ov = ovf  + ((size_t)dir * NB + b) * NHW;

    const int sx = tx0 + (t & (TS - 1));
    const int sy = ty0 + (t >> 5);
    const int hw = sy * NW + sx;

    const float fy_d = fb[hw];
    const float fx_d = fb[NHW + hw];
    const float4 p4 = pm[hw];

    const float px = fx_d + (float)sx;
    const float py = fy_d + (float)sy;
    const float x0f = floorf(px), y0f = floorf(py);
    const int ix0 = (int)x0f, iy0 = (int)y0f;
    const float wx1 = px - x0f, wy1 = py - y0f;
    const float wx0 = 1.0f - wx1, wy0 = 1.0f - wy1;
    const int lx0 = ix0 - tx0;
    const int ly0 = iy0 - ty0;

#pragma unroll
    for (int dy = 0; dy < 2; ++dy) {
        const int ly = ly0 + dy;
        const float wyd = dy ? wy1 : wy0;
#pragma unroll
        for (int dx = 0; dx < 2; ++dx) {
            const int lx = lx0 + dx;
            const float wg = wyd * (dx ? wx1 : wx0);
            if ((unsigned)lx < TS && (unsigned)ly < TS) {
                const int cell = (ly << 5) + lx;
                atomicAdd(&acc[0][cell], p4.x * wg);
                atomicAdd(&acc[1][cell], p4.y * wg);
                atomicAdd(&acc[2][cell], p4.z * wg);
                atomicAdd(&acc[3][cell], p4.w * wg);
            } else {
                const int yi = iy0 + dy;
                const int xi = ix0 + dx;
                if (yi >= 0 && yi < NH && xi >= 0 && xi < NW) {
                    float* p = (float*)(ov + (yi * NW + xi));
                    atomicAdd(p + 0, p4.x * wg);
                    atomicAdd(p + 1, p4.y * wg);
                    atomicAdd(p + 2, p4.z * wg);
                    atomicAdd(p + 3, p4.w * wg);
                }
            }
        }
    }
    __syncthreads();

    // ---- flush own tile: one PLAIN coalesced float4 store per pixel ----
    a4[hw] = make_float4(acc[0][t], acc[1][t], acc[2][t], acc[3][t]);
}

// Merge overflow into acc4 and emit a PLANAR w plane for morph staging.
__global__ __launch_bounds__(256) void merge_kernel(
        float4* __restrict__ acc4, const float4* __restrict__ ovf,
        float* __restrict__ wpl) {
    const size_t total = (size_t)2 * NB * NHW;
    for (size_t i = (size_t)blockIdx.x * blockDim.x + threadIdx.x; i < total;
         i += (size_t)gridDim.x * blockDim.x) {
        float4 a = acc4[i];
        float4 o = ovf[i];
        a.x += o.x; a.y += o.y; a.z += o.z; a.w += o.w;
        acc4[i] = a;
        wpl[i] = a.w;
    }
}

// Fused: erode (min, +inf pad) -> dilate (max, -inf pad) of both occupancy
// masks + final blend + output store. Occupancy from PLANAR w plane;
// colors/denominator from merged acc4. Staged path covers p<=8 (k<=17).
__global__ __launch_bounds__(256) void morph_compose_kernel(
        const float4* __restrict__ acc4, const float* __restrict__ wpl,
        float* __restrict__ out, const int* __restrict__ kptr) {
    __shared__ float occA[64 * 64], occB[64 * 64];
    __shared__ float erA[48 * 48], erB[48 * 48];

    const int t = threadIdx.x;
    const int b = blockIdx.z;
    const int x0 = blockIdx.x * 32;
    const int y0 = blockIdx.y * 32;
    const int k = *kptr;
    const int p = k >> 1;

    const float* wa = wpl + (size_t)b * NHW;                    // dir 0
    const float* wb = wpl + ((size_t)NB + b) * NHW;             // dir 1

    float mA[4], mB[4];

    if (p <= 8) {
        const int OS = 32 + 4 * p;
        const int ES = 32 + 2 * p;
        for (int i = t; i < OS * OS; i += 256) {
            int sx = x0 - 2 * p + (i % OS);
            int sy = y0 - 2 * p + (i / OS);
            float oa = 1.0f, ob = 1.0f;   // +inf pad for erode == treat OOB as occupied
            if (sx >= 0 && sx < NW && sy >= 0 && sy < NH) {
                int o = sy * NW + sx;
                oa = (wa[o] != 0.0f) ? 1.0f : 0.0f;
                ob = (wb[o] != 0.0f) ? 1.0f : 0.0f;
            }
            occA[i] = oa; occB[i] = ob;
        }
        __syncthreads();
        for (int i = t; i < ES * ES; i += 256) {
            int lx = i % ES, ly = i / ES;
            int ex = x0 - p + lx, ey = y0 - p + ly;
            float ea = 0.0f, eb = 0.0f;   // -inf pad for dilate == 0 (er in {0,1})
            if (ex >= 0 && ex < NW && ey >= 0 && ey < NH) {
                ea = 1.0f; eb = 1.0f;
                for (int dy = -p; dy <= p; ++dy)
                    for (int dx = -p; dx <= p; ++dx) {
                        int oi = (ly + p + dy) * OS + (lx + p + dx);
                        ea = fminf(ea, occA[oi]);
                        eb = fminf(eb, occB[oi]);
                    }
            }
            erA[i] = ea; erB[i] = eb;
        }
        __syncthreads();
#pragma unroll
        for (int r = 0; r < 4; ++r) {
            int lx = t & 31, ly = (t >> 5) + r * 8;
            float ma = 0.0f, mb = 0.0f;
            for (int dy = -p; dy <= p; ++dy)
                for (int dx = -p; dx <= p; ++dx) {
                    int ei = (ly + p + dy) * ES + (lx + p + dx);
                    ma = fmaxf(ma, erA[ei]);
                    mb = fmaxf(mb, erB[ei]);
                }
            mA[r] = ma; mB[r] = mb;
        }
    } else {
        // brute-force fallback, never taken for k<=17; correctness insurance
#pragma unroll
        for (int r = 0; r < 4; ++r) {
            int x = x0 + (t & 31), y = y0 + (t >> 5) + r * 8;
            float ma = 0.0f, mb = 0.0f;
            for (int dy2 = -p; dy2 <= p; ++dy2) {
                int qy = y + dy2; if (qy < 0 || qy >= NH) continue;
                for (int dx2 = -p; dx2 <= p; ++dx2) {
                    int qx = x + dx2; if (qx < 0 || qx >= NW) continue;
                    if (ma >= 1.0f && mb >= 1.0f) break;
                    float ea = 1.0f, eb = 1.0f;
                    for (int dy = -p; dy <= p; ++dy) {
                        int yy = qy + dy; if (yy < 0 || yy >= NH) continue;
                        for (int dx = -p; dx <= p; ++dx) {
                            int xx = qx + dx; if (xx < 0 || xx >= NW) continue;
                            int o = yy * NW + xx;
                            if (wa[o] == 0.0f) ea = 0.0f;
                            if (wb[o] == 0.0f) eb = 0.0f;
                        }
                    }
                    ma = fmaxf(ma, ea);
                    mb = fmaxf(mb, eb);
                }
            }
            mA[r] = ma; mB[r] = mb;
        }
    }

    const float4* a0 = acc4 + (size_t)b * NHW;
    const float4* a1 = acc4 + ((size_t)NB + b) * NHW;
    float* o0 = out + (size_t)b * 4 * NHW;
    float* o1 = out + (size_t)NB * 4 * NHW + (size_t)b * 4 * NHW;

#pragma unroll
    for (int r = 0; r < 4; ++r) {
        int lx = t & 31, ly = (t >> 5) + r * 8;
        int x = x0 + lx, y = y0 + ly;
        int hw = y * NW + x;
        float4 v0 = a0[hw];
        float4 v1 = a1[hw];
        float d0 = (v0.w == 0.0f) ? 1.0f : v0.w;
        float d1 = (v1.w == 0.0f) ? 1.0f : v1.w;
        float m0 = mA[r], m1 = mB[r];
        float w00 = v0.x / d0, w01 = v0.y / d0, w02 = v0.z / d0;
        float w10 = v1.x / d1, w11 = v1.y / d1, w12 = v1.z / d1;
        o0[hw]           = m0 * w00 + (1.0f - m0) * w10;
        o0[NHW + hw]     = m0 * w01 + (1.0f - m0) * w11;
        o0[2 * NHW + hw] = m0 * w02 + (1.0f - m0) * w12;
        o0[3 * NHW + hw] = m0;
        o1[hw]           = m1 * w10 + (1.0f - m1) * w00;
        o1[NHW + hw]     = m1 * w11 + (1.0f - m1) * w01;
        o1[2 * NHW + hw] = m1 * w12 + (1.0f - m1) * w02;
        o1[3 * NHW + hw] = m1;
    }
}

extern "C" void kernel_launch(void* const* d_in, const int* in_sizes, int n_in,
                              void* d_out, int out_size, void* d_ws, size_t ws_size,
                              hipStream_t stream) {
    const float* I0  = (const float*)d_in[0];
    const float* I1  = (const float*)d_in[1];
    const float* f01 = (const float*)d_in[2];
    const float* f10 = (const float*)d_in[3];
    const int*  kptr = (const int*)d_in[4];

    float* ws = (float*)d_ws;
    const size_t n = (size_t)NB * NHW;
    // ws layout, 16n floats total (proven footprint):
    //   [0, 8n)   pm0|pm1 (float4) during wmap+splat; wplane (2n floats)
    //             after splat (overlays dead pm).
    //   [8n, 16n) acc4 (2n float4, both dirs). lab (6n) overlays it during
    //             the lab/wmap phase; acc4 is fully written by flush stores.
    // d_out (8n floats = 2n float4) doubles as the zeroed overflow buffer
    // during splat; merge folds it into acc4 before morph overwrites d_out.
    float4* pm0  = (float4*)ws;               // [0, 4n)
    float4* pm1  = (float4*)(ws + 4 * n);     // [4n, 8n)
    float*  wpl  = ws;                        // [0, 2n)  after splat
    float4* acc4 = (float4*)(ws + 8 * n);     // [8n, 16n)
    float*  lab0 = ws + 8 * n;                // [8n, 11n)  overlays acc4
    float*  lab1 = ws + 11 * n;               // [11n, 14n) overlays acc4
    float4* ovf  = (float4*)d_out;            // overflow scratch (zeroed)

    const int T = 256;
    int gLab = (2 * NB * NHW + T - 1) / T;
    dim3 gW(NW / 32, NH / 8, 2 * NB);
    dim3 gTile(NW / TS, NH / TS, 2 * NB);
    dim3 gCmp(NW / 32, NH / 32, NB);

    hipMemsetAsync(d_out, 0, 8 * n * sizeof(float), stream);   // zero overflow
    lab_kernel<<<gLab, T, 0, stream>>>(I0, I1, lab0, lab1);
    wmap_kernel<<<gW, T, 0, stream>>>(lab0, lab1, I0, I1, f01, f10, pm0, pm1);
    splat_own_kernel<<<gTile, 1024, 0, stream>>>(pm0, pm1, f01, f10, acc4, ovf);
    merge_kernel<<<4096, T, 0, stream>>>(acc4, ovf, wpl);
    morph_compose_kernel<<<gCmp, T, 0, stream>>>(acc4, wpl, (float*)d_out, kptr);
}

// Round 15
// 754.184 us; speedup vs baseline: 3.7003x; 3.7003x over previous
//
#include <hip/hip_runtime.h>

#define NB 4
#define NH 1024
#define NW 1024
#define NHW (NH * NW)

#define TS 32          // owned output tile side
#define HP 16          // halo
#define SRCS 64        // source region side = TS + 2*HP
#define SRC_PX (SRCS * SRCS)   // 4096
#define TILE_PX (TS * TS)      // 1024

__device__ __forceinline__ float srgb2lin(float v) {
    return v > 0.04045f ? powf((v + 0.055f) * (1.0f / 1.055f), 2.4f) : v * (1.0f / 12.92f);
}

__device__ __forceinline__ float labf(float t) {
    return t > 0.008856f ? cbrtf(t) : 7.787f * t + 4.0f / 29.0f;
}

// Compute Lab for both images, INTERLEAVED (hw,3) output for gather locality.
__global__ void lab_kernel(const float* __restrict__ I0, const float* __restrict__ I1,
                           float* __restrict__ lab0, float* __restrict__ lab1) {
    int idx = blockIdx.x * blockDim.x + threadIdx.x;
    const int total = 2 * NB * NHW;
    if (idx >= total) return;
    int img = (idx >= NB * NHW) ? 1 : 0;
    int p = idx - img * NB * NHW;
    int b = p / NHW;
    int hw = p - b * NHW;
    const float* src = (img ? I1 : I0) + (size_t)b * 3 * NHW + hw;
    float* dst = (img ? lab1 : lab0) + ((size_t)b * NHW + hw) * 3;

    float r = srgb2lin(src[0]);
    float g = srgb2lin(src[NHW]);
    float bl = srgb2lin(src[2 * NHW]);

    float X = (0.412453f * r + 0.35758f * g + 0.180423f * bl) * (1.0f / 0.95047f);
    float Y = (0.212671f * r + 0.71516f * g + 0.072169f * bl);
    float Z = (0.019334f * r + 0.119193f * g + 0.950227f * bl) * (1.0f / 1.08883f);

    float fx = labf(X);
    float fy = labf(Y);
    float fz = labf(Z);

    dst[0] = 116.0f * fy - 16.0f;
    dst[1] = 500.0f * (fx - fy);
    dst[2] = 200.0f * (fy - fz);
}

// z-metric + exp + premultiply, both directions in one launch (z in [0,2*NB)).
__global__ __launch_bounds__(256) void wmap_kernel(
        const float* __restrict__ lab0, const float* __restrict__ lab1,
        const float* __restrict__ I0, const float* __restrict__ I1,
        const float* __restrict__ f01, const float* __restrict__ f10,
        float4* __restrict__ pm0, float4* __restrict__ pm1) {
    const int z = blockIdx.z;
    const int dir = z >> 2;            // NB == 4
    const int b = z & (NB - 1);
    const int tx = threadIdx.x & 31;
    const int ty = threadIdx.x >> 5;
    const int x = blockIdx.x * 32 + tx;
    const int y = blockIdx.y * 8 + ty;
    const int hw = y * NW + x;

    const float* la  = (dir ? lab1 : lab0) + (size_t)b * NHW * 3;
    const float* lb  = (dir ? lab0 : lab1) + (size_t)b * NHW * 3;
    const float* img = (dir ? I1 : I0) + (size_t)b * 3 * NHW;
    const float* fb  = (dir ? f10 : f01) + (size_t)b * 2 * NHW;
    float4* pm = (dir ? pm1 : pm0) + (size_t)b * NHW;

    const float fy_d = fb[hw];
    const float fx_d = fb[NHW + hw];

    float base_y = -1.0f + 2.0f * (float)y / (float)(NH - 1);
    float base_x = -1.0f + 2.0f * (float)x / (float)(NW - 1);
    float gy = 2.0f * fy_d / (float)NH + base_y;
    float gx = 2.0f * fx_d / (float)NW + base_x;
    float ys = fminf(fmaxf(((gy + 1.0f) * (float)NH - 1.0f) * 0.5f, 0.0f), (float)(NH - 1));
    float xs = fminf(fmaxf(((gx + 1.0f) * (float)NW - 1.0f) * 0.5f, 0.0f), (float)(NW - 1));
    float y0f = floorf(ys), x0f = floorf(xs);
    int y0 = (int)y0f, x0 = (int)x0f;
    int y1 = min(y0 + 1, NH - 1), x1 = min(x0 + 1, NW - 1);
    float wy = ys - y0f, wx = xs - x0f;

    const float* p00 = lb + (size_t)(y0 * NW + x0) * 3;
    const float* p01 = lb + (size_t)(y0 * NW + x1) * 3;
    const float* p10 = lb + (size_t)(y1 * NW + x0) * 3;
    const float* p11 = lb + (size_t)(y1 * NW + x1) * 3;
    const float* pa  = la + (size_t)hw * 3;

    float ss = 0.0f;
#pragma unroll
    for (int c = 0; c < 3; ++c) {
        float top = p00[c] * (1.0f - wx) + p01[c] * wx;
        float bot = p10[c] * (1.0f - wx) + p11[c] * wx;
        float v = top * (1.0f - wy) + bot * wy;
        float d = pa[c] - v;
        ss += d * d;
    }
    float w = expf(-0.1f * sqrtf(ss));

    pm[hw] = make_float4(img[hw] * w, img[NHW + hw] * w, img[2 * NHW + hw] * w, w);
}

// BIN + GATHER splat. Phase 1 (bin): each region source is linked (by
// atomicExch on a per-floor-cell head) into one of 33x33 lists; slot id =
// region index (no allocator). Phase 2 (gather): each thread owns one
// output cell, walks the 4 lists {c-1,c}^2, recomputes wg in IDENTICAL f32
// arithmetic, sums in registers, plain-stores acc4. This replaces 16
// ds-atomic lane-ops/px (~3cy each, the measured r2-r12 floor) with ~1
// atomicExch + plain LDS traffic. Covered<=>binned is equivalent to r12's
// covered check, so uncovered taps use the same ovf float4 fallback.
__global__ __launch_bounds__(1024, 2) void splat_bin_kernel(
        const float4* __restrict__ pm0, const float4* __restrict__ pm1,
        const float* __restrict__ f01, const float* __restrict__ f10,
        float4* __restrict__ acc4,    // [2*NB*NHW) float4, dir-major
        float4* __restrict__ ovf) {   // [2*NB*NHW) float4, dir-major (zeroed)
    __shared__ unsigned       head[33 * 33];   // 4356 B, sentinel 0xFFFF
    __shared__ unsigned short nxt[SRC_PX];     // 8 KB
    __shared__ float2         flows[SRC_PX];   // 32 KB

    const int t = threadIdx.x;
    const int z = blockIdx.z;
    const int dir = z >> 2;
    const int b = z & (NB - 1);
    const int tx0 = blockIdx.x * TS;
    const int ty0 = blockIdx.y * TS;
    const int ox = tx0 - HP;
    const int oy = ty0 - HP;

    for (int i = t; i < 33 * 33; i += 1024) head[i] = 0xFFFFu;
    __syncthreads();

    const float4* pm = (dir ? pm1 : pm0) + (size_t)b * NHW;
    const float* fb  = (dir ? f10 : f01) + (size_t)b * 2 * NHW;
    float4* a4 = acc4 + ((size_t)dir * NB + b) * NHW;
    float4* ov = ovf  + ((size_t)dir * NB + b) * NHW;

    // ---- phase 1: bin sources by floor(target) cell ----
#pragma unroll
    for (int kk = 0; kk < 4; ++kk) {
        const int i = t + kk * 1024;   // SRC_PX == 4 * 1024
        const int rx = i & (SRCS - 1);
        const int ry = i >> 6;
        const int sx = ox + rx;
        const int sy = oy + ry;
        if (sx < 0 || sx >= NW || sy < 0 || sy >= NH) continue;
        const int hw = sy * NW + sx;

        const float fy_d = fb[hw];
        const float fx_d = fb[NHW + hw];
        flows[i] = make_float2(fx_d, fy_d);

        const float px = fx_d + (float)sx;
        const float py = fy_d + (float)sy;
        const int fcx = (int)floorf(px);
        const int fcy = (int)floorf(py);
        const int mx = fcx - tx0;      // margin-relative floor cell
        const int my = fcy - ty0;

        if (mx >= -1 && mx < TS && my >= -1 && my < TS) {
            unsigned old = atomicExch(&head[(my + 1) * 33 + (mx + 1)], (unsigned)i);
            nxt[i] = (unsigned short)old;
        }

        // interior-owned, uncovered taps -> ovf (identical to r12 logic)
        const bool interior = (rx >= HP) && (rx < HP + TS) && (ry >= HP) && (ry < HP + TS);
        if (interior) {
            float4 p4; bool loaded = false;
#pragma unroll
            for (int dy = 0; dy < 2; ++dy) {
                const int yi = fcy + dy;
                if (yi < 0 || yi >= NH) continue;
                const float wgy = 1.0f - fabsf(py - (float)yi);
#pragma unroll
                for (int dx = 0; dx < 2; ++dx) {
                    const int xi = fcx + dx;
                    if (xi < 0 || xi >= NW) continue;
                    const int ttx0 = xi & ~(TS - 1);
                    const int tty0 = yi & ~(TS - 1);
                    const bool covered = (sx >= ttx0 - HP) && (sx < ttx0 + TS + HP) &&
                                         (sy >= tty0 - HP) && (sy < tty0 + TS + HP);
                    if (!covered) {
                        if (!loaded) { p4 = pm[hw]; loaded = true; }
                        const float wg = wgy * (1.0f - fabsf(px - (float)xi));
                        float* p = (float*)(ov + (yi * NW + xi));
                        atomicAdd(p + 0, p4.x * wg);
                        atomicAdd(p + 1, p4.y * wg);
                        atomicAdd(p + 2, p4.z * wg);
                        atomicAdd(p + 3, p4.w * wg);
                    }
                }
            }
        }
    }
    __syncthreads();

    // ---- phase 2: gather own cell from the 4 relevant lists ----
    {
        const int lx = t & (TS - 1);
        const int ly = t >> 5;
        const int cx = tx0 + lx;
        const int cy = ty0 + ly;
        const float cxf = (float)cx;
        const float cyf = (float)cy;

        float sx_ = 0.0f, sy_ = 0.0f, sz_ = 0.0f, sw_ = 0.0f;

#pragma unroll
        for (int dy = 0; dy < 2; ++dy) {
#pragma unroll
            for (int dx = 0; dx < 2; ++dx) {
                unsigned e = head[(ly + 1 - dy) * 33 + (lx + 1 - dx)];
                int guard = SRC_PX;
                while (e != 0xFFFFu && --guard >= 0) {
                    const float2 f = flows[e];
                    const int rx = e & (SRCS - 1);
                    const int ry = (int)e >> 6;
                    const int sxx = ox + rx;
                    const int syy = oy + ry;
                    const float px = f.x + (float)sxx;
                    const float py = f.y + (float)syy;
                    const float wg = (1.0f - fabsf(px - cxf)) * (1.0f - fabsf(py - cyf));
                    const float4 p4 = pm[syy * NW + sxx];
                    sx_ += p4.x * wg;
                    sy_ += p4.y * wg;
                    sz_ += p4.z * wg;
                    sw_ += p4.w * wg;
                    e = nxt[e];
                }
            }
        }
        a4[cy * NW + cx] = make_float4(sx_, sy_, sz_, sw_);
    }
}

// Merge overflow into acc4 and emit a PLANAR w plane for morph staging.
__global__ __launch_bounds__(256) void merge_kernel(
        float4* __restrict__ acc4, const float4* __restrict__ ovf,
        float* __restrict__ wpl) {
    const size_t total = (size_t)2 * NB * NHW;
    for (size_t i = (size_t)blockIdx.x * blockDim.x + threadIdx.x; i < total;
         i += (size_t)gridDim.x * blockDim.x) {
        float4 a = acc4[i];
        float4 o = ovf[i];
        a.x += o.x; a.y += o.y; a.z += o.z; a.w += o.w;
        acc4[i] = a;
        wpl[i] = a.w;
    }
}

// Fused: erode (min, +inf pad) -> dilate (max, -inf pad) of both occupancy
// masks + final blend + output store. Occupancy from PLANAR w plane;
// colors/denominator from merged acc4. Staged path covers p<=8 (k<=17).
__global__ __launch_bounds__(256) void morph_compose_kernel(
        const float4* __restrict__ acc4, const float* __restrict__ wpl,
        float* __restrict__ out, const int* __restrict__ kptr) {
    __shared__ float occA[64 * 64], occB[64 * 64];
    __shared__ float erA[48 * 48], erB[48 * 48];

    const int t = threadIdx.x;
    const int b = blockIdx.z;
    const int x0 = blockIdx.x * 32;
    const int y0 = blockIdx.y * 32;
    const int k = *kptr;
    const int p = k >> 1;

    const float* wa = wpl + (size_t)b * NHW;                    // dir 0
    const float* wb = wpl + ((size_t)NB + b) * NHW;             // dir 1

    float mA[4], mB[4];

    if (p <= 8) {
        const int OS = 32 + 4 * p;
        const int ES = 32 + 2 * p;
        for (int i = t; i < OS * OS; i += 256) {
            int sx = x0 - 2 * p + (i % OS);
            int sy = y0 - 2 * p + (i / OS);
            float oa = 1.0f, ob = 1.0f;   // +inf pad for erode == treat OOB as occupied
            if (sx >= 0 && sx < NW && sy >= 0 && sy < NH) {
                int o = sy * NW + sx;
                oa = (wa[o] != 0.0f) ? 1.0f : 0.0f;
                ob = (wb[o] != 0.0f) ? 1.0f : 0.0f;
            }
            occA[i] = oa; occB[i] = ob;
        }
        __syncthreads();
        for (int i = t; i < ES * ES; i += 256) {
            int lx = i % ES, ly = i / ES;
            int ex = x0 - p + lx, ey = y0 - p + ly;
            float ea = 0.0f, eb = 0.0f;   // -inf pad for dilate == 0 (er in {0,1})
            if (ex >= 0 && ex < NW && ey >= 0 && ey < NH) {
                ea = 1.0f; eb = 1.0f;
                for (int dy = -p; dy <= p; ++dy)
                    for (int dx = -p; dx <= p; ++dx) {
                        int oi = (ly + p + dy) * OS + (lx + p + dx);
                        ea = fminf(ea, occA[oi]);
                        eb = fminf(eb, occB[oi]);
                    }
            }
            erA[i] = ea; erB[i] = eb;
        }
        __syncthreads();
#pragma unroll
        for (int r = 0; r < 4; ++r) {
            int lx = t & 31, ly = (t >> 5) + r * 8;
            float ma = 0.0f, mb = 0.0f;
            for (int dy = -p; dy <= p; ++dy)
                for (int dx = -p; dx <= p; ++dx) {
                    int ei = (ly + p + dy) * ES + (lx + p + dx);
                    ma = fmaxf(ma, erA[ei]);
                    mb = fmaxf(mb, erB[ei]);
                }
            mA[r] = ma; mB[r] = mb;
        }
    } else {
        // brute-force fallback, never taken for k<=17; correctness insurance
#pragma unroll
        for (int r = 0; r < 4; ++r) {
            int x = x0 + (t & 31), y = y0 + (t >> 5) + r * 8;
            float ma = 0.0f, mb = 0.0f;
            for (int dy2 = -p; dy2 <= p; ++dy2) {
                int qy = y + dy2; if (qy < 0 || qy >= NH) continue;
                for (int dx2 = -p; dx2 <= p; ++dx2) {
                    int qx = x + dx2; if (qx < 0 || qx >= NW) continue;
                    if (ma >= 1.0f && mb >= 1.0f) break;
                    float ea = 1.0f, eb = 1.0f;
                    for (int dy = -p; dy <= p; ++dy) {
                        int yy = qy + dy; if (yy < 0 || yy >= NH) continue;
                        for (int dx = -p; dx <= p; ++dx) {
                            int xx = qx + dx; if (xx < 0 || xx >= NW) continue;
                            int o = yy * NW + xx;
                            if (wa[o] == 0.0f) ea = 0.0f;
                            if (wb[o] == 0.0f) eb = 0.0f;
                        }
                    }
                    ma = fmaxf(ma, ea);
                    mb = fmaxf(mb, eb);
                }
            }
            mA[r] = ma; mB[r] = mb;
        }
    }

    const float4* a0 = acc4 + (size_t)b * NHW;
    const float4* a1 = acc4 + ((size_t)NB + b) * NHW;
    float* o0 = out + (size_t)b * 4 * NHW;
    float* o1 = out + (size_t)NB * 4 * NHW + (size_t)b * 4 * NHW;

#pragma unroll
    for (int r = 0; r < 4; ++r) {
        int lx = t & 31, ly = (t >> 5) + r * 8;
        int x = x0 + lx, y = y0 + ly;
        int hw = y * NW + x;
        float4 v0 = a0[hw];
        float4 v1 = a1[hw];
        float d0 = (v0.w == 0.0f) ? 1.0f : v0.w;
        float d1 = (v1.w == 0.0f) ? 1.0f : v1.w;
        float m0 = mA[r], m1 = mB[r];
        float w00 = v0.x / d0, w01 = v0.y / d0, w02 = v0.z / d0;
        float w10 = v1.x / d1, w11 = v1.y / d1, w12 = v1.z / d1;
        o0[hw]           = m0 * w00 + (1.0f - m0) * w10;
        o0[NHW + hw]     = m0 * w01 + (1.0f - m0) * w11;
        o0[2 * NHW + hw] = m0 * w02 + (1.0f - m0) * w12;
        o0[3 * NHW + hw] = m0;
        o1[hw]           = m1 * w10 + (1.0f - m1) * w00;
        o1[NHW + hw]     = m1 * w11 + (1.0f - m1) * w01;
        o1[2 * NHW + hw] = m1 * w12 + (1.0f - m1) * w02;
        o1[3 * NHW + hw] = m1;
    }
}

extern "C" void kernel_launch(void* const* d_in, const int* in_sizes, int n_in,
                              void* d_out, int out_size, void* d_ws, size_t ws_size,
                              hipStream_t stream) {
    const float* I0  = (const float*)d_in[0];
    const float* I1  = (const float*)d_in[1];
    const float* f01 = (const float*)d_in[2];
    const float* f10 = (const float*)d_in[3];
    const int*  kptr = (const int*)d_in[4];

    float* ws = (float*)d_ws;
    const size_t n = (size_t)NB * NHW;
    // ws layout, 16n floats total (proven footprint):
    //   [0, 8n)   pm0|pm1 (float4) during wmap+splat; wplane (2n floats)
    //             after splat (overlays dead pm).
    //   [8n, 16n) acc4 (2n float4, both dirs). lab (6n) overlays it during
    //             the lab/wmap phase; acc4 is fully written by gather stores.
    // d_out (8n floats = 2n float4) doubles as the zeroed overflow buffer
    // during splat; merge folds it into acc4 before morph overwrites d_out.
    float4* pm0  = (float4*)ws;               // [0, 4n)
    float4* pm1  = (float4*)(ws + 4 * n);     // [4n, 8n)
    float*  wpl  = ws;                        // [0, 2n)  after splat
    float4* acc4 = (float4*)(ws + 8 * n);     // [8n, 16n)
    float*  lab0 = ws + 8 * n;                // [8n, 11n)  overlays acc4
    float*  lab1 = ws + 11 * n;               // [11n, 14n) overlays acc4
    float4* ovf  = (float4*)d_out;            // overflow scratch (zeroed)

    const int T = 256;
    int gLab = (2 * NB * NHW + T - 1) / T;
    dim3 gW(NW / 32, NH / 8, 2 * NB);
    dim3 gTile(NW / TS, NH / TS, 2 * NB);
    dim3 gCmp(NW / 32, NH / 32, NB);

    hipMemsetAsync(d_out, 0, 8 * n * sizeof(float), stream);   // zero overflow
    lab_kernel<<<gLab, T, 0, stream>>>(I0, I1, lab0, lab1);
    wmap_kernel<<<gW, T, 0, stream>>>(lab0, lab1, I0, I1, f01, f10, pm0, pm1);
    splat_bin_kernel<<<gTile, 1024, 0, stream>>>(pm0, pm1, f01, f10, acc4, ovf);
    merge_kernel<<<4096, T, 0, stream>>>(acc4, ovf, wpl);
    morph_compose_kernel<<<gCmp, T, 0, stream>>>(acc4, wpl, (float*)d_out, kptr);
}

// Round 16
// 750.956 us; speedup vs baseline: 3.7162x; 1.0043x over previous
//
#include <hip/hip_runtime.h>

#define NB 4
#define NH 1024
#define NW 1024
#define NHW (NH * NW)

#define TS 32          // owned output tile side
#define HP 16          // halo
#define SRCS 64        // source region side = TS + 2*HP
#define SRC_PX (SRCS * SRCS)   // 4096
#define TILE_PX (TS * TS)      // 1024

__device__ __forceinline__ float srgb2lin(float v) {
    return v > 0.04045f ? powf((v + 0.055f) * (1.0f / 1.055f), 2.4f) : v * (1.0f / 12.92f);
}

__device__ __forceinline__ float labf(float t) {
    return t > 0.008856f ? cbrtf(t) : 7.787f * t + 4.0f / 29.0f;
}

// Compute Lab for both images, FLOAT4-padded (hw,4) for single-load gathers.
__global__ void lab_kernel(const float* __restrict__ I0, const float* __restrict__ I1,
                           float4* __restrict__ lab0, float4* __restrict__ lab1) {
    int idx = blockIdx.x * blockDim.x + threadIdx.x;
    const int total = 2 * NB * NHW;
    if (idx >= total) return;
    int img = (idx >= NB * NHW) ? 1 : 0;
    int p = idx - img * NB * NHW;
    int b = p / NHW;
    int hw = p - b * NHW;
    const float* src = (img ? I1 : I0) + (size_t)b * 3 * NHW + hw;
    float4* dst = (img ? lab1 : lab0) + ((size_t)b * NHW + hw);

    float r = srgb2lin(src[0]);
    float g = srgb2lin(src[NHW]);
    float bl = srgb2lin(src[2 * NHW]);

    float X = (0.412453f * r + 0.35758f * g + 0.180423f * bl) * (1.0f / 0.95047f);
    float Y = (0.212671f * r + 0.71516f * g + 0.072169f * bl);
    float Z = (0.019334f * r + 0.119193f * g + 0.950227f * bl) * (1.0f / 1.08883f);

    float fx = labf(X);
    float fy = labf(Y);
    float fz = labf(Z);

    *dst = make_float4(116.0f * fy - 16.0f, 500.0f * (fx - fy), 200.0f * (fy - fz), 0.0f);
}

// z-metric + exp + premultiply, both directions in one launch (z in [0,2*NB)).
// lab4 padding: each bilinear corner is ONE 16B load (was 3 scalar loads).
__global__ __launch_bounds__(256) void wmap_kernel(
        const float4* __restrict__ lab0, const float4* __restrict__ lab1,
        const float* __restrict__ I0, const float* __restrict__ I1,
        const float* __restrict__ f01, const float* __restrict__ f10,
        float4* __restrict__ pm0, float4* __restrict__ pm1) {
    const int z = blockIdx.z;
    const int dir = z >> 2;            // NB == 4
    const int b = z & (NB - 1);
    const int tx = threadIdx.x & 31;
    const int ty = threadIdx.x >> 5;
    const int x = blockIdx.x * 32 + tx;
    const int y = blockIdx.y * 8 + ty;
    const int hw = y * NW + x;

    const float4* la  = (dir ? lab1 : lab0) + (size_t)b * NHW;
    const float4* lb  = (dir ? lab0 : lab1) + (size_t)b * NHW;
    const float* img = (dir ? I1 : I0) + (size_t)b * 3 * NHW;
    const float* fb  = (dir ? f10 : f01) + (size_t)b * 2 * NHW;
    float4* pm = (dir ? pm1 : pm0) + (size_t)b * NHW;

    const float fy_d = fb[hw];
    const float fx_d = fb[NHW + hw];

    float base_y = -1.0f + 2.0f * (float)y / (float)(NH - 1);
    float base_x = -1.0f + 2.0f * (float)x / (float)(NW - 1);
    float gy = 2.0f * fy_d / (float)NH + base_y;
    float gx = 2.0f * fx_d / (float)NW + base_x;
    float ys = fminf(fmaxf(((gy + 1.0f) * (float)NH - 1.0f) * 0.5f, 0.0f), (float)(NH - 1));
    float xs = fminf(fmaxf(((gx + 1.0f) * (float)NW - 1.0f) * 0.5f, 0.0f), (float)(NW - 1));
    float y0f = floorf(ys), x0f = floorf(xs);
    int y0 = (int)y0f, x0 = (int)x0f;
    int y1 = min(y0 + 1, NH - 1), x1 = min(x0 + 1, NW - 1);
    float wy = ys - y0f, wx = xs - x0f;

    const float4 p00 = lb[y0 * NW + x0];
    const float4 p01 = lb[y0 * NW + x1];
    const float4 p10 = lb[y1 * NW + x0];
    const float4 p11 = lb[y1 * NW + x1];
    const float4 pa  = la[hw];

    float3 top, bot, v;
    top.x = p00.x * (1.0f - wx) + p01.x * wx;
    top.y = p00.y * (1.0f - wx) + p01.y * wx;
    top.z = p00.z * (1.0f - wx) + p01.z * wx;
    bot.x = p10.x * (1.0f - wx) + p11.x * wx;
    bot.y = p10.y * (1.0f - wx) + p11.y * wx;
    bot.z = p10.z * (1.0f - wx) + p11.z * wx;
    v.x = top.x * (1.0f - wy) + bot.x * wy;
    v.y = top.y * (1.0f - wy) + bot.y * wy;
    v.z = top.z * (1.0f - wy) + bot.z * wy;
    float dx_ = pa.x - v.x, dy_ = pa.y - v.y, dz_ = pa.z - v.z;
    float ss = dx_ * dx_ + dy_ * dy_ + dz_ * dz_;
    float w = expf(-0.1f * sqrtf(ss));

    pm[hw] = make_float4(img[hw] * w, img[NHW + hw] * w, img[2 * NHW + hw] * w, w);
}

// BIN + GATHER splat (r14 structure, unchanged; 253us, VALU-bound).
__global__ __launch_bounds__(1024, 2) void splat_bin_kernel(
        const float4* __restrict__ pm0, const float4* __restrict__ pm1,
        const float* __restrict__ f01, const float* __restrict__ f10,
        float4* __restrict__ acc4,    // [2*NB*NHW) float4, dir-major
        float4* __restrict__ ovf) {   // [2*NB*NHW) float4, dir-major (zeroed)
    __shared__ unsigned       head[33 * 33];   // sentinel 0xFFFF
    __shared__ unsigned short nxt[SRC_PX];
    __shared__ float2         flows[SRC_PX];

    const int t = threadIdx.x;
    const int z = blockIdx.z;
    const int dir = z >> 2;
    const int b = z & (NB - 1);
    const int tx0 = blockIdx.x * TS;
    const int ty0 = blockIdx.y * TS;
    const int ox = tx0 - HP;
    const int oy = ty0 - HP;

    for (int i = t; i < 33 * 33; i += 1024) head[i] = 0xFFFFu;
    __syncthreads();

    const float4* pm = (dir ? pm1 : pm0) + (size_t)b * NHW;
    const float* fb  = (dir ? f10 : f01) + (size_t)b * 2 * NHW;
    float4* a4 = acc4 + ((size_t)dir * NB + b) * NHW;
    float4* ov = ovf  + ((size_t)dir * NB + b) * NHW;

    // ---- phase 1: bin sources by floor(target) cell ----
#pragma unroll
    for (int kk = 0; kk < 4; ++kk) {
        const int i = t + kk * 1024;   // SRC_PX == 4 * 1024
        const int rx = i & (SRCS - 1);
        const int ry = i >> 6;
        const int sx = ox + rx;
        const int sy = oy + ry;
        if (sx < 0 || sx >= NW || sy < 0 || sy >= NH) continue;
        const int hw = sy * NW + sx;

        const float fy_d = fb[hw];
        const float fx_d = fb[NHW + hw];
        flows[i] = make_float2(fx_d, fy_d);

        const float px = fx_d + (float)sx;
        const float py = fy_d + (float)sy;
        const int fcx = (int)floorf(px);
        const int fcy = (int)floorf(py);
        const int mx = fcx - tx0;      // margin-relative floor cell
        const int my = fcy - ty0;

        if (mx >= -1 && mx < TS && my >= -1 && my < TS) {
            unsigned old = atomicExch(&head[(my + 1) * 33 + (mx + 1)], (unsigned)i);
            nxt[i] = (unsigned short)old;
        }

        // interior-owned, uncovered taps -> ovf (identical to r12 logic)
        const bool interior = (rx >= HP) && (rx < HP + TS) && (ry >= HP) && (ry < HP + TS);
        if (interior) {
            float4 p4; bool loaded = false;
#pragma unroll
            for (int dy = 0; dy < 2; ++dy) {
                const int yi = fcy + dy;
                if (yi < 0 || yi >= NH) continue;
                const float wgy = 1.0f - fabsf(py - (float)yi);
#pragma unroll
                for (int dx = 0; dx < 2; ++dx) {
                    const int xi = fcx + dx;
                    if (xi < 0 || xi >= NW) continue;
                    const int ttx0 = xi & ~(TS - 1);
                    const int tty0 = yi & ~(TS - 1);
                    const bool covered = (sx >= ttx0 - HP) && (sx < ttx0 + TS + HP) &&
                                         (sy >= tty0 - HP) && (sy < tty0 + TS + HP);
                    if (!covered) {
                        if (!loaded) { p4 = pm[hw]; loaded = true; }
                        const float wg = wgy * (1.0f - fabsf(px - (float)xi));
                        float* p = (float*)(ov + (yi * NW + xi));
                        atomicAdd(p + 0, p4.x * wg);
                        atomicAdd(p + 1, p4.y * wg);
                        atomicAdd(p + 2, p4.z * wg);
                        atomicAdd(p + 3, p4.w * wg);
                    }
                }
            }
        }
    }
    __syncthreads();

    // ---- phase 2: gather own cell from the 4 relevant lists ----
    {
        const int lx = t & (TS - 1);
        const int ly = t >> 5;
        const int cx = tx0 + lx;
        const int cy = ty0 + ly;
        const float cxf = (float)cx;
        const float cyf = (float)cy;

        float sx_ = 0.0f, sy_ = 0.0f, sz_ = 0.0f, sw_ = 0.0f;

#pragma unroll
        for (int dy = 0; dy < 2; ++dy) {
#pragma unroll
            for (int dx = 0; dx < 2; ++dx) {
                unsigned e = head[(ly + 1 - dy) * 33 + (lx + 1 - dx)];
                int guard = SRC_PX;
                while (e != 0xFFFFu && --guard >= 0) {
                    const float2 f = flows[e];
                    const int rx = e & (SRCS - 1);
                    const int ry = (int)e >> 6;
                    const int sxx = ox + rx;
                    const int syy = oy + ry;
                    const float px = f.x + (float)sxx;
                    const float py = f.y + (float)syy;
                    const float wg = (1.0f - fabsf(px - cxf)) * (1.0f - fabsf(py - cyf));
                    const float4 p4 = pm[syy * NW + sxx];
                    sx_ += p4.x * wg;
                    sy_ += p4.y * wg;
                    sz_ += p4.z * wg;
                    sw_ += p4.w * wg;
                    e = nxt[e];
                }
            }
        }
        a4[cy * NW + cx] = make_float4(sx_, sy_, sz_, sw_);
    }
}

// Merge overflow into acc4 and emit a PLANAR w plane for morph staging.
__global__ __launch_bounds__(256) void merge_kernel(
        float4* __restrict__ acc4, const float4* __restrict__ ovf,
        float* __restrict__ wpl) {
    const size_t total = (size_t)2 * NB * NHW;
    for (size_t i = (size_t)blockIdx.x * blockDim.x + threadIdx.x; i < total;
         i += (size_t)gridDim.x * blockDim.x) {
        float4 a = acc4[i];
        float4 o = ovf[i];
        a.x += o.x; a.y += o.y; a.z += o.z; a.w += o.w;
        acc4[i] = a;
        wpl[i] = a.w;
    }
}

// Fused morph (SEPARABLE erode+dilate: 2*(2p+1) ops instead of (2p+1)^2 per
// stage) + final blend + output store. Staged path covers p<=8 (k<=17).
// Buffers per direction: bufO (occ -> er), bufH (hmin -> hmax). 56 KB total.
__global__ __launch_bounds__(256) void morph_compose_kernel(
        const float4* __restrict__ acc4, const float* __restrict__ wpl,
        float* __restrict__ out, const int* __restrict__ kptr) {
    __shared__ float bufOA[64 * 64], bufOB[64 * 64];   // occ (OS*OS) -> er (ES*ES)
    __shared__ float bufHA[64 * 48], bufHB[64 * 48];   // hmin (OS*ES) -> hmax (ES*32)

    const int t = threadIdx.x;
    const int b = blockIdx.z;
    const int x0 = blockIdx.x * 32;
    const int y0 = blockIdx.y * 32;
    const int k = *kptr;
    const int p = k >> 1;

    const float* wa = wpl + (size_t)b * NHW;                    // dir 0
    const float* wb = wpl + ((size_t)NB + b) * NHW;             // dir 1

    float mA[4], mB[4];

    if (p <= 8) {
        const int OS = 32 + 4 * p;
        const int ES = 32 + 2 * p;
        const int KW = 2 * p + 1;
        // stage occupancy (+inf pad: OOB = 1)
        for (int i = t; i < OS * OS; i += 256) {
            int sx = x0 - 2 * p + (i % OS);
            int sy = y0 - 2 * p + (i / OS);
            float oa = 1.0f, ob = 1.0f;
            if (sx >= 0 && sx < NW && sy >= 0 && sy < NH) {
                int o = sy * NW + sx;
                oa = (wa[o] != 0.0f) ? 1.0f : 0.0f;
                ob = (wb[o] != 0.0f) ? 1.0f : 0.0f;
            }
            bufOA[i] = oa; bufOB[i] = ob;
        }
        __syncthreads();
        // horizontal min: OS rows x ES cols
        for (int i = t; i < OS * ES; i += 256) {
            int y = i / ES, x = i % ES;
            float ma = 1.0f, mb = 1.0f;
            for (int d = 0; d < KW; ++d) {
                ma = fminf(ma, bufOA[y * OS + x + d]);
                mb = fminf(mb, bufOB[y * OS + x + d]);
            }
            bufHA[i] = ma; bufHB[i] = mb;
        }
        __syncthreads();
        // vertical min -> erode result (0 outside image: dilate -inf pad)
        for (int i = t; i < ES * ES; i += 256) {
            int ly = i / ES, lx = i % ES;
            int ex = x0 - p + lx, ey = y0 - p + ly;
            float ea = 0.0f, eb = 0.0f;
            if (ex >= 0 && ex < NW && ey >= 0 && ey < NH) {
                ea = 1.0f; eb = 1.0f;
                for (int d = 0; d < KW; ++d) {
                    ea = fminf(ea, bufHA[(ly + d) * ES + lx]);
                    eb = fminf(eb, bufHB[(ly + d) * ES + lx]);
                }
            }
            bufOA[i] = ea; bufOB[i] = eb;   // bufO reused for er
        }
        __syncthreads();
        // horizontal max: ES rows x 32 cols
        for (int i = t; i < ES * 32; i += 256) {
            int y = i >> 5, x = i & 31;
            float ma = 0.0f, mb = 0.0f;
            for (int d = 0; d < KW; ++d) {
                ma = fmaxf(ma, bufOA[y * ES + x + d]);
                mb = fmaxf(mb, bufOB[y * ES + x + d]);
            }
            bufHA[i] = ma; bufHB[i] = mb;   // bufH reused for hmax
        }
        __syncthreads();
        // vertical max -> dilate result for own 4 px
#pragma unroll
        for (int r = 0; r < 4; ++r) {
            int lx = t & 31, ly = (t >> 5) + r * 8;
            float ma = 0.0f, mb = 0.0f;
            for (int d = 0; d < KW; ++d) {
                ma = fmaxf(ma, bufHA[((ly + d) << 5) + lx]);
                mb = fmaxf(mb, bufHB[((ly + d) << 5) + lx]);
            }
            mA[r] = ma; mB[r] = mb;
        }
    } else {
        // brute-force fallback, never taken for k<=17; correctness insurance
#pragma unroll
        for (int r = 0; r < 4; ++r) {
            int x = x0 + (t & 31), y = y0 + (t >> 5) + r * 8;
            float ma = 0.0f, mb = 0.0f;
            for (int dy2 = -p; dy2 <= p; ++dy2) {
                int qy = y + dy2; if (qy < 0 || qy >= NH) continue;
                for (int dx2 = -p; dx2 <= p; ++dx2) {
                    int qx = x + dx2; if (qx < 0 || qx >= NW) continue;
                    if (ma >= 1.0f && mb >= 1.0f) break;
                    float ea = 1.0f, eb = 1.0f;
                    for (int dy = -p; dy <= p; ++dy) {
                        int yy = qy + dy; if (yy < 0 || yy >= NH) continue;
                        for (int dx = -p; dx <= p; ++dx) {
                            int xx = qx + dx; if (xx < 0 || xx >= NW) continue;
                            int o = yy * NW + xx;
                            if (wa[o] == 0.0f) ea = 0.0f;
                            if (wb[o] == 0.0f) eb = 0.0f;
                        }
                    }
                    ma = fmaxf(ma, ea);
                    mb = fmaxf(mb, eb);
                }
            }
            mA[r] = ma; mB[r] = mb;
        }
    }

    const float4* a0 = acc4 + (size_t)b * NHW;
    const float4* a1 = acc4 + ((size_t)NB + b) * NHW;
    float* o0 = out + (size_t)b * 4 * NHW;
    float* o1 = out + (size_t)NB * 4 * NHW + (size_t)b * 4 * NHW;

#pragma unroll
    for (int r = 0; r < 4; ++r) {
        int lx = t & 31, ly = (t >> 5) + r * 8;
        int x = x0 + lx, y = y0 + ly;
        int hw = y * NW + x;
        float4 v0 = a0[hw];
        float4 v1 = a1[hw];
        float d0 = (v0.w == 0.0f) ? 1.0f : v0.w;
        float d1 = (v1.w == 0.0f) ? 1.0f : v1.w;
        float m0 = mA[r], m1 = mB[r];
        float w00 = v0.x / d0, w01 = v0.y / d0, w02 = v0.z / d0;
        float w10 = v1.x / d1, w11 = v1.y / d1, w12 = v1.z / d1;
        o0[hw]           = m0 * w00 + (1.0f - m0) * w10;
        o0[NHW + hw]     = m0 * w01 + (1.0f - m0) * w11;
        o0[2 * NHW + hw] = m0 * w02 + (1.0f - m0) * w12;
        o0[3 * NHW + hw] = m0;
        o1[hw]           = m1 * w10 + (1.0f - m1) * w00;
        o1[NHW + hw]     = m1 * w11 + (1.0f - m1) * w01;
        o1[2 * NHW + hw] = m1 * w12 + (1.0f - m1) * w02;
        o1[3 * NHW + hw] = m1;
    }
}

extern "C" void kernel_launch(void* const* d_in, const int* in_sizes, int n_in,
                              void* d_out, int out_size, void* d_ws, size_t ws_size,
                              hipStream_t stream) {
    const float* I0  = (const float*)d_in[0];
    const float* I1  = (const float*)d_in[1];
    const float* f01 = (const float*)d_in[2];
    const float* f10 = (const float*)d_in[3];
    const int*  kptr = (const int*)d_in[4];

    float* ws = (float*)d_ws;
    const size_t n = (size_t)NB * NHW;
    // ws layout, 16n floats total (proven footprint):
    //   [0, 8n)   pm0|pm1 (float4) during wmap+splat; wplane (2n floats)
    //             after splat (overlays dead pm).
    //   [8n, 16n) lab4_0|lab4_1 (float4-padded lab) during lab/wmap;
    //             acc4 (2n float4) after — fully written by gather stores.
    // d_out (8n floats = 2n float4) doubles as the zeroed overflow buffer
    // during splat; merge folds it into acc4 before morph overwrites d_out.
    float4* pm0   = (float4*)ws;               // [0, 4n)
    float4* pm1   = (float4*)(ws + 4 * n);     // [4n, 8n)
    float*  wpl   = ws;                        // [0, 2n)  after splat
    float4* lab40 = (float4*)(ws + 8 * n);     // [8n, 12n)
    float4* lab41 = (float4*)(ws + 12 * n);    // [12n, 16n)
    float4* acc4  = (float4*)(ws + 8 * n);     // [8n, 16n) overlays lab4
    float4* ovf   = (float4*)d_out;            // overflow scratch (zeroed)

    const int T = 256;
    int gLab = (2 * NB * NHW + T - 1) / T;
    dim3 gW(NW / 32, NH / 8, 2 * NB);
    dim3 gTile(NW / TS, NH / TS, 2 * NB);
    dim3 gCmp(NW / 32, NH / 32, NB);

    hipMemsetAsync(d_out, 0, 8 * n * sizeof(float), stream);   // zero overflow
    lab_kernel<<<gLab, T, 0, stream>>>(I0, I1, lab40, lab41);
    wmap_kernel<<<gW, T, 0, stream>>>(lab40, lab41, I0, I1, f01, f10, pm0, pm1);
    splat_bin_kernel<<<gTile, 1024, 0, stream>>>(pm0, pm1, f01, f10, acc4, ovf);
    merge_kernel<<<4096, T, 0, stream>>>(acc4, ovf, wpl);
    morph_compose_kernel<<<gCmp, T, 0, stream>>>(acc4, wpl, (float*)d_out, kptr);
}

// Round 17
// 727.154 us; speedup vs baseline: 3.8378x; 1.0327x over previous
//
#include <hip/hip_runtime.h>

#define NB 4
#define NH 1024
#define NW 1024
#define NHW (NH * NW)

#define TS 32          // owned output tile side
#define HP 16          // halo
#define SRCS 64        // source region side = TS + 2*HP
#define SRC_PX (SRCS * SRCS)   // 4096
#define TILE_PX (TS * TS)      // 1024

__device__ __forceinline__ float srgb2lin(float v) {
    return v > 0.04045f ? powf((v + 0.055f) * (1.0f / 1.055f), 2.4f) : v * (1.0f / 12.92f);
}

__device__ __forceinline__ float labf(float t) {
    return t > 0.008856f ? cbrtf(t) : 7.787f * t + 4.0f / 29.0f;
}

// Compute Lab for both images, FLOAT4-padded (hw,4) for single-load gathers.
__global__ void lab_kernel(const float* __restrict__ I0, const float* __restrict__ I1,
                           float4* __restrict__ lab0, float4* __restrict__ lab1) {
    int idx = blockIdx.x * blockDim.x + threadIdx.x;
    const int total = 2 * NB * NHW;
    if (idx >= total) return;
    int img = (idx >= NB * NHW) ? 1 : 0;
    int p = idx - img * NB * NHW;
    int b = p / NHW;
    int hw = p - b * NHW;
    const float* src = (img ? I1 : I0) + (size_t)b * 3 * NHW + hw;
    float4* dst = (img ? lab1 : lab0) + ((size_t)b * NHW + hw);

    float r = srgb2lin(src[0]);
    float g = srgb2lin(src[NHW]);
    float bl = srgb2lin(src[2 * NHW]);

    float X = (0.412453f * r + 0.35758f * g + 0.180423f * bl) * (1.0f / 0.95047f);
    float Y = (0.212671f * r + 0.71516f * g + 0.072169f * bl);
    float Z = (0.019334f * r + 0.119193f * g + 0.950227f * bl) * (1.0f / 1.08883f);

    float fx = labf(X);
    float fy = labf(Y);
    float fz = labf(Z);

    *dst = make_float4(116.0f * fy - 16.0f, 500.0f * (fx - fy), 200.0f * (fy - fz), 0.0f);
}

// z-metric + exp + premultiply, both directions in one launch (z in [0,2*NB)).
__global__ __launch_bounds__(256) void wmap_kernel(
        const float4* __restrict__ lab0, const float4* __restrict__ lab1,
        const float* __restrict__ I0, const float* __restrict__ I1,
        const float* __restrict__ f01, const float* __restrict__ f10,
        float4* __restrict__ pm0, float4* __restrict__ pm1) {
    const int z = blockIdx.z;
    const int dir = z >> 2;            // NB == 4
    const int b = z & (NB - 1);
    const int tx = threadIdx.x & 31;
    const int ty = threadIdx.x >> 5;
    const int x = blockIdx.x * 32 + tx;
    const int y = blockIdx.y * 8 + ty;
    const int hw = y * NW + x;

    const float4* la  = (dir ? lab1 : lab0) + (size_t)b * NHW;
    const float4* lb  = (dir ? lab0 : lab1) + (size_t)b * NHW;
    const float* img = (dir ? I1 : I0) + (size_t)b * 3 * NHW;
    const float* fb  = (dir ? f10 : f01) + (size_t)b * 2 * NHW;
    float4* pm = (dir ? pm1 : pm0) + (size_t)b * NHW;

    const float fy_d = fb[hw];
    const float fx_d = fb[NHW + hw];

    float base_y = -1.0f + 2.0f * (float)y / (float)(NH - 1);
    float base_x = -1.0f + 2.0f * (float)x / (float)(NW - 1);
    float gy = 2.0f * fy_d / (float)NH + base_y;
    float gx = 2.0f * fx_d / (float)NW + base_x;
    float ys = fminf(fmaxf(((gy + 1.0f) * (float)NH - 1.0f) * 0.5f, 0.0f), (float)(NH - 1));
    float xs = fminf(fmaxf(((gx + 1.0f) * (float)NW - 1.0f) * 0.5f, 0.0f), (float)(NW - 1));
    float y0f = floorf(ys), x0f = floorf(xs);
    int y0 = (int)y0f, x0 = (int)x0f;
    int y1 = min(y0 + 1, NH - 1), x1 = min(x0 + 1, NW - 1);
    float wy = ys - y0f, wx = xs - x0f;

    const float4 p00 = lb[y0 * NW + x0];
    const float4 p01 = lb[y0 * NW + x1];
    const float4 p10 = lb[y1 * NW + x0];
    const float4 p11 = lb[y1 * NW + x1];
    const float4 pa  = la[hw];

    float3 top, bot, v;
    top.x = p00.x * (1.0f - wx) + p01.x * wx;
    top.y = p00.y * (1.0f - wx) + p01.y * wx;
    top.z = p00.z * (1.0f - wx) + p01.z * wx;
    bot.x = p10.x * (1.0f - wx) + p11.x * wx;
    bot.y = p10.y * (1.0f - wx) + p11.y * wx;
    bot.z = p10.z * (1.0f - wx) + p11.z * wx;
    v.x = top.x * (1.0f - wy) + bot.x * wy;
    v.y = top.y * (1.0f - wy) + bot.y * wy;
    v.z = top.z * (1.0f - wy) + bot.z * wy;
    float dx_ = pa.x - v.x, dy_ = pa.y - v.y, dz_ = pa.z - v.z;
    float ss = dx_ * dx_ + dy_ * dy_ + dz_ * dz_;
    float w = expf(-0.1f * sqrtf(ss));

    pm[hw] = make_float4(img[hw] * w, img[NHW + hw] * w, img[2 * NHW + hw] * w, w);
}

// BIN + GATHER splat (r14 structure) + fallback pre-test: uncovered taps
// require max(|fx|,|fy|) > 15 (|flow|<=15 => xi-sx in [-16,16] =>
// sx-ttx0 in [-16,47] => always covered), so ~88% of interior sources skip
// the 4-way covered-check entirely.
__global__ __launch_bounds__(1024, 2) void splat_bin_kernel(
        const float4* __restrict__ pm0, const float4* __restrict__ pm1,
        const float* __restrict__ f01, const float* __restrict__ f10,
        float4* __restrict__ acc4,    // [2*NB*NHW) float4, dir-major
        float4* __restrict__ ovf) {   // [2*NB*NHW) float4, dir-major (zeroed)
    __shared__ unsigned       head[33 * 33];   // sentinel 0xFFFF
    __shared__ unsigned short nxt[SRC_PX];
    __shared__ float2         flows[SRC_PX];

    const int t = threadIdx.x;
    const int z = blockIdx.z;
    const int dir = z >> 2;
    const int b = z & (NB - 1);
    const int tx0 = blockIdx.x * TS;
    const int ty0 = blockIdx.y * TS;
    const int ox = tx0 - HP;
    const int oy = ty0 - HP;

    for (int i = t; i < 33 * 33; i += 1024) head[i] = 0xFFFFu;
    __syncthreads();

    const float4* pm = (dir ? pm1 : pm0) + (size_t)b * NHW;
    const float* fb  = (dir ? f10 : f01) + (size_t)b * 2 * NHW;
    float4* a4 = acc4 + ((size_t)dir * NB + b) * NHW;
    float4* ov = ovf  + ((size_t)dir * NB + b) * NHW;

    // ---- phase 1: bin sources by floor(target) cell ----
#pragma unroll
    for (int kk = 0; kk < 4; ++kk) {
        const int i = t + kk * 1024;   // SRC_PX == 4 * 1024
        const int rx = i & (SRCS - 1);
        const int ry = i >> 6;
        const int sx = ox + rx;
        const int sy = oy + ry;
        if (sx < 0 || sx >= NW || sy < 0 || sy >= NH) continue;
        const int hw = sy * NW + sx;

        const float fy_d = fb[hw];
        const float fx_d = fb[NHW + hw];
        flows[i] = make_float2(fx_d, fy_d);

        const float px = fx_d + (float)sx;
        const float py = fy_d + (float)sy;
        const int fcx = (int)floorf(px);
        const int fcy = (int)floorf(py);
        const int mx = fcx - tx0;      // margin-relative floor cell
        const int my = fcy - ty0;

        if (mx >= -1 && mx < TS && my >= -1 && my < TS) {
            unsigned old = atomicExch(&head[(my + 1) * 33 + (mx + 1)], (unsigned)i);
            nxt[i] = (unsigned short)old;
        }

        // interior-owned, uncovered taps -> ovf. Pre-test skips provably
        // covered sources (max|flow| <= 15).
        const bool interior = (rx >= HP) && (rx < HP + TS) && (ry >= HP) && (ry < HP + TS);
        if (interior && fmaxf(fabsf(fx_d), fabsf(fy_d)) > 15.0f) {
            float4 p4; bool loaded = false;
#pragma unroll
            for (int dy = 0; dy < 2; ++dy) {
                const int yi = fcy + dy;
                if (yi < 0 || yi >= NH) continue;
                const float wgy = 1.0f - fabsf(py - (float)yi);
#pragma unroll
                for (int dx = 0; dx < 2; ++dx) {
                    const int xi = fcx + dx;
                    if (xi < 0 || xi >= NW) continue;
                    const int ttx0 = xi & ~(TS - 1);
                    const int tty0 = yi & ~(TS - 1);
                    const bool covered = (sx >= ttx0 - HP) && (sx < ttx0 + TS + HP) &&
                                         (sy >= tty0 - HP) && (sy < tty0 + TS + HP);
                    if (!covered) {
                        if (!loaded) { p4 = pm[hw]; loaded = true; }
                        const float wg = wgy * (1.0f - fabsf(px - (float)xi));
                        float* p = (float*)(ov + (yi * NW + xi));
                        atomicAdd(p + 0, p4.x * wg);
                        atomicAdd(p + 1, p4.y * wg);
                        atomicAdd(p + 2, p4.z * wg);
                        atomicAdd(p + 3, p4.w * wg);
                    }
                }
            }
        }
    }
    __syncthreads();

    // ---- phase 2: gather own cell from the 4 relevant lists ----
    {
        const int lx = t & (TS - 1);
        const int ly = t >> 5;
        const int cx = tx0 + lx;
        const int cy = ty0 + ly;
        const float cxf = (float)cx;
        const float cyf = (float)cy;

        float sx_ = 0.0f, sy_ = 0.0f, sz_ = 0.0f, sw_ = 0.0f;

#pragma unroll
        for (int dy = 0; dy < 2; ++dy) {
#pragma unroll
            for (int dx = 0; dx < 2; ++dx) {
                unsigned e = head[(ly + 1 - dy) * 33 + (lx + 1 - dx)];
                int guard = SRC_PX;
                while (e != 0xFFFFu && --guard >= 0) {
                    const float2 f = flows[e];
                    const int rx = e & (SRCS - 1);
                    const int ry = (int)e >> 6;
                    const int sxx = ox + rx;
                    const int syy = oy + ry;
                    const float px = f.x + (float)sxx;
                    const float py = f.y + (float)syy;
                    const float wg = (1.0f - fabsf(px - cxf)) * (1.0f - fabsf(py - cyf));
                    const float4 p4 = pm[syy * NW + sxx];
                    sx_ += p4.x * wg;
                    sy_ += p4.y * wg;
                    sz_ += p4.z * wg;
                    sw_ += p4.w * wg;
                    e = nxt[e];
                }
            }
        }
        a4[cy * NW + cx] = make_float4(sx_, sy_, sz_, sw_);
    }
}

// Merge overflow into acc4 and emit a PLANAR w plane (NON-FUSED path only).
__global__ __launch_bounds__(256) void merge_kernel(
        float4* __restrict__ acc4, const float4* __restrict__ ovf,
        float* __restrict__ wpl) {
    const size_t total = (size_t)2 * NB * NHW;
    for (size_t i = (size_t)blockIdx.x * blockDim.x + threadIdx.x; i < total;
         i += (size_t)gridDim.x * blockDim.x) {
        float4 a = acc4[i];
        float4 o = ovf[i];
        a.x += o.x; a.y += o.y; a.z += o.z; a.w += o.w;
        acc4[i] = a;
        wpl[i] = a.w;
    }
}

// Fused morph (separable erode+dilate) + blend + store.
// FUSED=true: reads acc4 + ovf directly (merge pass eliminated; occupancy
// test (a.w+o.w)!=0 is exact for non-negative floats, blend sums the pair —
// identical arithmetic to merge's fold). FUSED=false: r15 path (merged acc4
// + planar wpl). Staged path covers p<=8 (k<=17); brute-force beyond.
template <bool FUSED>
__global__ __launch_bounds__(256) void morph_compose_kernel(
        const float4* __restrict__ acc4, const float4* __restrict__ ovf,
        const float* __restrict__ wpl,
        float* __restrict__ out, const int* __restrict__ kptr) {
    __shared__ float bufOA[64 * 64], bufOB[64 * 64];   // occ (OS*OS) -> er (ES*ES)
    __shared__ float bufHA[64 * 48], bufHB[64 * 48];   // hmin (OS*ES) -> hmax (ES*32)

    const int t = threadIdx.x;
    const int b = blockIdx.z;
    const int x0 = blockIdx.x * 32;
    const int y0 = blockIdx.y * 32;
    const int k = *kptr;
    const int p = k >> 1;

    const float4* a0 = acc4 + (size_t)b * NHW;
    const float4* a1 = acc4 + ((size_t)NB + b) * NHW;
    const float4* v0p = FUSED ? (ovf + (size_t)b * NHW) : nullptr;
    const float4* v1p = FUSED ? (ovf + ((size_t)NB + b) * NHW) : nullptr;
    const float* wa = FUSED ? nullptr : (wpl + (size_t)b * NHW);
    const float* wb = FUSED ? nullptr : (wpl + ((size_t)NB + b) * NHW);

    float mA[4], mB[4];

    if (p <= 8) {
        const int OS = 32 + 4 * p;
        const int ES = 32 + 2 * p;
        const int KW = 2 * p + 1;
        // stage occupancy (+inf pad: OOB = 1)
        for (int i = t; i < OS * OS; i += 256) {
            int sx = x0 - 2 * p + (i % OS);
            int sy = y0 - 2 * p + (i / OS);
            float oa = 1.0f, ob = 1.0f;
            if (sx >= 0 && sx < NW && sy >= 0 && sy < NH) {
                int o = sy * NW + sx;
                float wA, wB;
                if (FUSED) {
                    wA = a0[o].w + v0p[o].w;
                    wB = a1[o].w + v1p[o].w;
                } else {
                    wA = wa[o];
                    wB = wb[o];
                }
                oa = (wA != 0.0f) ? 1.0f : 0.0f;
                ob = (wB != 0.0f) ? 1.0f : 0.0f;
            }
            bufOA[i] = oa; bufOB[i] = ob;
        }
        __syncthreads();
        // horizontal min: OS rows x ES cols
        for (int i = t; i < OS * ES; i += 256) {
            int y = i / ES, x = i % ES;
            float ma = 1.0f, mb = 1.0f;
            for (int d = 0; d < KW; ++d) {
                ma = fminf(ma, bufOA[y * OS + x + d]);
                mb = fminf(mb, bufOB[y * OS + x + d]);
            }
            bufHA[i] = ma; bufHB[i] = mb;
        }
        __syncthreads();
        // vertical min -> erode result (0 outside image: dilate -inf pad)
        for (int i = t; i < ES * ES; i += 256) {
            int ly = i / ES, lx = i % ES;
            int ex = x0 - p + lx, ey = y0 - p + ly;
            float ea = 0.0f, eb = 0.0f;
            if (ex >= 0 && ex < NW && ey >= 0 && ey < NH) {
                ea = 1.0f; eb = 1.0f;
                for (int d = 0; d < KW; ++d) {
                    ea = fminf(ea, bufHA[(ly + d) * ES + lx]);
                    eb = fminf(eb, bufHB[(ly + d) * ES + lx]);
                }
            }
            bufOA[i] = ea; bufOB[i] = eb;   // bufO reused for er
        }
        __syncthreads();
        // horizontal max: ES rows x 32 cols
        for (int i = t; i < ES * 32; i += 256) {
            int y = i >> 5, x = i & 31;
            float ma = 0.0f, mb = 0.0f;
            for (int d = 0; d < KW; ++d) {
                ma = fmaxf(ma, bufOA[y * ES + x + d]);
                mb = fmaxf(mb, bufOB[y * ES + x + d]);
            }
            bufHA[i] = ma; bufHB[i] = mb;   // bufH reused for hmax
        }
        __syncthreads();
        // vertical max -> dilate result for own 4 px
#pragma unroll
        for (int r = 0; r < 4; ++r) {
            int lx = t & 31, ly = (t >> 5) + r * 8;
            float ma = 0.0f, mb = 0.0f;
            for (int d = 0; d < KW; ++d) {
                ma = fmaxf(ma, bufHA[((ly + d) << 5) + lx]);
                mb = fmaxf(mb, bufHB[((ly + d) << 5) + lx]);
            }
            mA[r] = ma; mB[r] = mb;
        }
    } else {
        // brute-force fallback, never taken for k<=17; correctness insurance
#pragma unroll
        for (int r = 0; r < 4; ++r) {
            int x = x0 + (t & 31), y = y0 + (t >> 5) + r * 8;
            float ma = 0.0f, mb = 0.0f;
            for (int dy2 = -p; dy2 <= p; ++dy2) {
                int qy = y + dy2; if (qy < 0 || qy >= NH) continue;
                for (int dx2 = -p; dx2 <= p; ++dx2) {
                    int qx = x + dx2; if (qx < 0 || qx >= NW) continue;
                    if (ma >= 1.0f && mb >= 1.0f) break;
                    float ea = 1.0f, eb = 1.0f;
                    for (int dy = -p; dy <= p; ++dy) {
                        int yy = qy + dy; if (yy < 0 || yy >= NH) continue;
                        for (int dx = -p; dx <= p; ++dx) {
                            int xx = qx + dx; if (xx < 0 || xx >= NW) continue;
                            int o = yy * NW + xx;
                            float wA, wB;
                            if (FUSED) {
                                wA = a0[o].w + v0p[o].w;
                                wB = a1[o].w + v1p[o].w;
                            } else {
                                wA = wa[o];
                                wB = wb[o];
                            }
                            if (wA == 0.0f) ea = 0.0f;
                            if (wB == 0.0f) eb = 0.0f;
                        }
                    }
                    ma = fmaxf(ma, ea);
                    mb = fmaxf(mb, eb);
                }
            }
            mA[r] = ma; mB[r] = mb;
        }
    }

    float* o0 = out + (size_t)b * 4 * NHW;
    float* o1 = out + (size_t)NB * 4 * NHW + (size_t)b * 4 * NHW;

#pragma unroll
    for (int r = 0; r < 4; ++r) {
        int lx = t & 31, ly = (t >> 5) + r * 8;
        int x = x0 + lx, y = y0 + ly;
        int hw = y * NW + x;
        float4 v0 = a0[hw];
        float4 v1 = a1[hw];
        if (FUSED) {
            float4 q0 = v0p[hw];
            float4 q1 = v1p[hw];
            v0.x += q0.x; v0.y += q0.y; v0.z += q0.z; v0.w += q0.w;
            v1.x += q1.x; v1.y += q1.y; v1.z += q1.z; v1.w += q1.w;
        }
        float d0 = (v0.w == 0.0f) ? 1.0f : v0.w;
        float d1 = (v1.w == 0.0f) ? 1.0f : v1.w;
        float m0 = mA[r], m1 = mB[r];
        float w00 = v0.x / d0, w01 = v0.y / d0, w02 = v0.z / d0;
        float w10 = v1.x / d1, w11 = v1.y / d1, w12 = v1.z / d1;
        o0[hw]           = m0 * w00 + (1.0f - m0) * w10;
        o0[NHW + hw]     = m0 * w01 + (1.0f - m0) * w11;
        o0[2 * NHW + hw] = m0 * w02 + (1.0f - m0) * w12;
        o0[3 * NHW + hw] = m0;
        o1[hw]           = m1 * w10 + (1.0f - m1) * w00;
        o1[NHW + hw]     = m1 * w11 + (1.0f - m1) * w01;
        o1[2 * NHW + hw] = m1 * w12 + (1.0f - m1) * w02;
        o1[3 * NHW + hw] = m1;
    }
}

extern "C" void kernel_launch(void* const* d_in, const int* in_sizes, int n_in,
                              void* d_out, int out_size, void* d_ws, size_t ws_size,
                              hipStream_t stream) {
    const float* I0  = (const float*)d_in[0];
    const float* I1  = (const float*)d_in[1];
    const float* f01 = (const float*)d_in[2];
    const float* f10 = (const float*)d_in[3];
    const int*  kptr = (const int*)d_in[4];

    float* ws = (float*)d_ws;
    const size_t n = (size_t)NB * NHW;
    // ws layout:
    //   [0, 8n)   pm0|pm1 (float4) during wmap+splat; wpl (2n) after splat
    //             (non-fused path only).
    //   [8n, 16n) lab4 during lab/wmap; acc4 (2n float4) after (fully
    //             written by gather stores — no memset needed).
    //   [16n,24n) ovf — ONLY if ws is large enough (fused path: morph reads
    //             acc4+ovf directly, merge pass eliminated). Otherwise ovf
    //             lives in d_out and the r15 merge+morph path runs.
    float4* pm0   = (float4*)ws;               // [0, 4n)
    float4* pm1   = (float4*)(ws + 4 * n);     // [4n, 8n)
    float*  wpl   = ws;                        // [0, 2n)  after splat
    float4* lab40 = (float4*)(ws + 8 * n);     // [8n, 12n)
    float4* lab41 = (float4*)(ws + 12 * n);    // [12n, 16n)
    float4* acc4  = (float4*)(ws + 8 * n);     // [8n, 16n) overlays lab4

    const bool fused = ws_size >= (size_t)24 * n * sizeof(float);
    float4* ovf = fused ? (float4*)(ws + 16 * n) : (float4*)d_out;

    const int T = 256;
    int gLab = (2 * NB * NHW + T - 1) / T;
    dim3 gW(NW / 32, NH / 8, 2 * NB);
    dim3 gTile(NW / TS, NH / TS, 2 * NB);
    dim3 gCmp(NW / 32, NH / 32, NB);

    hipMemsetAsync(ovf, 0, 8 * n * sizeof(float), stream);   // zero overflow
    lab_kernel<<<gLab, T, 0, stream>>>(I0, I1, lab40, lab41);
    wmap_kernel<<<gW, T, 0, stream>>>(lab40, lab41, I0, I1, f01, f10, pm0, pm1);
    splat_bin_kernel<<<gTile, 1024, 0, stream>>>(pm0, pm1, f01, f10, acc4, ovf);
    if (fused) {
        morph_compose_kernel<true><<<gCmp, T, 0, stream>>>(
            acc4, ovf, nullptr, (float*)d_out, kptr);
    } else {
        merge_kernel<<<4096, T, 0, stream>>>(acc4, ovf, wpl);
        morph_compose_kernel<false><<<gCmp, T, 0, stream>>>(
            acc4, nullptr, wpl, (float*)d_out, kptr);
    }
}